// Round 11
// baseline (162.656 us; speedup 1.0000x reference)
//
#include <hip/hip_runtime.h>
#include <stdint.h>

#define NSEQ 2048

typedef __attribute__((ext_vector_type(4))) float f32x4;
typedef __attribute__((ext_vector_type(8))) short s16x8;
typedef _Float16 f16x8 __attribute__((ext_vector_type(8)));
typedef _Float16 h16x2 __attribute__((ext_vector_type(2)));
typedef unsigned int u32;
typedef __attribute__((ext_vector_type(2))) unsigned int u32x2;

// workspace byte offsets
#define OFF_PO  0u            // [4 split][16 bh][2048][64] f16 = 16 MB
#define OFF_M   16777216u     // [4][16][2048] f32 running-max (log2 domain), 512 KB
#define OFF_L   17301504u     // [4][16][2048] f32 running-sum, 512 KB
#define OFF_QR  17825792u     // [16][2048][64] f16, 4 MB
#define OFF_KR  22020096u     // [16][2048][64]
#define OFF_VT  26214400u     // [16][64][2048]
#define OFF_W   30408704u     // 4 * 65536 f16 = 512 KB (ws end ~30.9 MB)

__device__ __forceinline__ short f2h(float f) {
  _Float16 h = (_Float16)f;
  return __builtin_bit_cast(short, h);
}
__device__ __forceinline__ float h2f(short s) {
  return (float)__builtin_bit_cast(_Float16, s);
}
// 128B-row tiles ([*][64] f16): classic ^(row&7) on the 16B slot
__device__ __forceinline__ int swz128(int row, int slot) {
  return row * 128 + ((slot ^ (row & 7)) << 4);
}
#define MFMA(a, b, c) __builtin_amdgcn_mfma_f32_16x16x32_f16(a, b, c, 0, 0, 0)

// ---------------- kernel 0: weight cast (+ Wm reorder to k = h*64+d) ----------------
__global__ void k_convw(const float* __restrict__ Wq, const float* __restrict__ Wk,
                        const float* __restrict__ Wv, const float* __restrict__ Wm,
                        char* __restrict__ ws) {
  int o = blockIdx.x, which = blockIdx.y, i = threadIdx.x;
  const float* src = which == 0 ? Wq : which == 1 ? Wk : which == 2 ? Wv : Wm;
  short* dst = (short*)(ws + OFF_W) + which * 65536;
  // Wm_r[o][h*64+d] = Wm[o][d*4+h]
  float val = (which < 3) ? src[o * 256 + i] : src[o * 256 + ((i & 63) << 2) + (i >> 6)];
  dst[o * 256 + i] = f2h(val);
}

// ---- kernel 1: QKV projection, transpose-cast FUSED (reads f32 x directly) ---------
// XCD chunk-swizzle: yo fastest so the 4 o-tile siblings (same x-tile) share an XCD L2
__global__ __launch_bounds__(256) void k_proj(const float* __restrict__ q,
    const float* __restrict__ k, const float* __restrict__ v,
    const float* __restrict__ enc, const float* __restrict__ bq,
    const float* __restrict__ bk, const float* __restrict__ bv, char* __restrict__ ws) {
  int hid = blockIdx.x + 32 * (blockIdx.y + 4 * blockIdx.z);   // 0..1535
  int fm = (hid & 7) * 192 + (hid >> 3);                       // bijective (1536%8==0)
  int yo = fm & 3, xn = (fm >> 2) & 31, z = fm >> 7;
  int proj = z >> 2, b = z & 3;
  const float* xs = proj == 0 ? q : (proj == 1 ? k : v);
  const short* W = (const short*)(ws + OFF_W) + proj * 65536;
  int o0 = yo * 64, n0 = xn * 64;
  __shared__ short As[64 * 64], Bs[64 * 64];
  __shared__ float ftile[64][65];
  int t = threadIdx.x, lane = t & 63, g = lane >> 4, c = lane & 15, wave = t >> 6;
  int wr = wave >> 1, wc = wave & 1;
  int row = t >> 2, seg = t & 3;
  int nl = t & 63, ib = (t >> 6) * 16;
  f32x4 acc[2][2] = {};
  for (int kk = 0; kk < 4; ++kk) {
    int koff = kk * 64;
    __syncthreads();
    // A: W f16 coalesced loads
    const short* wsrc = &W[(o0 + row) * 256 + koff];
    s16x8 wa0 = *(const s16x8*)(wsrc + seg * 8);
    s16x8 wa1 = *(const s16x8*)(wsrc + 32 + seg * 8);
    // x-tile f32, coalesced rows (transpose via padded LDS, k_trans pattern)
#pragma unroll
    for (int r = 0; r < 16; ++r)
      ftile[ib + r][nl] = xs[(b * 256 + koff + ib + r) * 2048 + n0 + nl];
    *(s16x8*)((char*)As + swz128(row, seg))     = wa0;
    *(s16x8*)((char*)As + swz128(row, 4 + seg)) = wa1;
    __syncthreads();
    // B: column reads (2-way, free), RNE cvt, k-contiguous vector writes
    int ic = seg * 16;
    short hb[16];
#pragma unroll
    for (int j = 0; j < 16; ++j) hb[j] = f2h(ftile[ic + j][row]);
    *(s16x8*)((char*)Bs + swz128(row, ic >> 3))       = *(const s16x8*)&hb[0];
    *(s16x8*)((char*)Bs + swz128(row, (ic >> 3) + 1)) = *(const s16x8*)&hb[8];
    __syncthreads();
#pragma unroll
    for (int ks = 0; ks < 2; ++ks) {
      f16x8 af[2], bfr[2];
#pragma unroll
      for (int f = 0; f < 2; ++f) {
        af[f]  = *(const f16x8*)((char*)As + swz128(wr * 32 + f * 16 + c, ks * 4 + g));
        bfr[f] = *(const f16x8*)((char*)Bs + swz128(wc * 32 + f * 16 + c, ks * 4 + g));
      }
#pragma unroll
      for (int i = 0; i < 2; ++i)
#pragma unroll
        for (int j = 0; j < 2; ++j)
          acc[i][j] = MFMA(af[i], bfr[j], acc[i][j]);
    }
  }
  const float* bias = proj == 0 ? bq : (proj == 1 ? bk : bv);
  if (proj < 2) {
    // RoPE: h = reg r, d = (o>>2); pair at lane^16, same reg.
    // fold 1/sqrt(64) * log2(e) into Q so softmax runs in exp2 domain
    short* dst0 = (short*)(ws + (proj == 0 ? OFF_QR : OFF_KR));
    float scale = proj == 0 ? 0.18033688f : 1.0f;
    float sgn = (g & 1) ? 1.0f : -1.0f;
#pragma unroll
    for (int i = 0; i < 2; ++i) {
      int ob = o0 + wr * 32 + i * 16 + g * 4;
      int d = ob >> 2;
#pragma unroll
      for (int j = 0; j < 2; ++j) {
        int n = n0 + wc * 32 + j * 16 + c;
        float cv = enc[n * 64 + d], sv = enc[131072 + n * 64 + d];
#pragma unroll
        for (int r = 0; r < 4; ++r) {
          float val = acc[i][j][r] + bias[ob + r];
          float par = __shfl_xor(val, 16, 64);
          float res = (val * cv + sgn * par * sv) * scale;
          dst0[((b * 4 + r) * 2048 + n) * 64 + d] = f2h(res);  // [bh][n][d]
        }
      }
    }
  } else {
    short* dst = (short*)(ws + OFF_VT);
#pragma unroll
    for (int i = 0; i < 2; ++i) {
      int ob = o0 + wr * 32 + i * 16 + g * 4;
      int d = ob >> 2;
#pragma unroll
      for (int j = 0; j < 2; ++j) {
        int n = n0 + wc * 32 + j * 16 + c;
#pragma unroll
        for (int r = 0; r < 4; ++r) {
          float val = acc[i][j][r] + bias[ob + r];
          dst[((b * 4 + r) * 64 + d) * 2048 + n] = f2h(val);  // [bh][d][m]
        }
      }
    }
  }
}

// ------- kernel 2: flash attention, split-KV x4, swapped QK^T, packed P-writes ------
__global__ __launch_bounds__(256, 4) void k_attn(char* __restrict__ ws) {
  int bh = blockIdx.y, ms = blockIdx.z;
  int t = threadIdx.x, wave = t >> 6, lane = t & 63, g = lane >> 4, c = lane & 15;
  int nw = blockIdx.x * 64 + wave * 16;  // this wave's 16 Q rows
  const short* Q = (const short*)(ws + OFF_QR) + bh * 131072;  // [2048][64]
  const short* K = (const short*)(ws + OFF_KR) + bh * 131072;
  const short* V = (const short*)(ws + OFF_VT) + bh * 131072;  // [64][2048]
  __shared__ short Ks[64 * 64], Vs[64 * 64], Ps[4][16 * 64];
  char* Pb = (char*)Ps[wave];
  f16x8 qf0 = *(const f16x8*)&Q[(nw + c) * 64 + g * 8];
  f16x8 qf1 = *(const f16x8*)&Q[(nw + c) * 64 + 32 + g * 8];
  f32x4 po[4] = {};
  float mrun = -1e30f, lrun = 0.f;   // per-lane scalars: softmax state of q-row (nw+c)
  int sr = t >> 3, sl = t & 7;
  const int mb = ms * 512;
  int bsrc = g * 16 + g * 4;         // shfl base: lane in same g-group holding row g*4+r

  s16x8 RA[4], RB[4];
  auto LD = [&](int m0, s16x8* R) {
    R[0] = *(const s16x8*)&K[(m0 + sr) * 64 + sl * 8];
    R[1] = *(const s16x8*)&K[(m0 + sr + 32) * 64 + sl * 8];
    R[2] = *(const s16x8*)&V[sr * 2048 + m0 + sl * 8];
    R[3] = *(const s16x8*)&V[(sr + 32) * 2048 + m0 + sl * 8];
  };
  auto ST = [&](const s16x8* R) {
    *(s16x8*)((char*)Ks + swz128(sr, sl))      = R[0];
    *(s16x8*)((char*)Ks + swz128(sr + 32, sl)) = R[1];
    *(s16x8*)((char*)Vs + swz128(sr, sl))      = R[2];
    *(s16x8*)((char*)Vs + swz128(sr + 32, sl)) = R[3];
  };
  auto COMPUTE = [&]() {
    // S^T = K Q^T : row = m = fj*16 + g*4 + r, col = n = c (lane-local q-row!)
    f32x4 s[4] = {};
    __builtin_amdgcn_s_setprio(1);
#pragma unroll
    for (int fj = 0; fj < 4; ++fj) {
      f16x8 k0 = *(const f16x8*)((char*)Ks + swz128(fj * 16 + c, g));
      f16x8 k1 = *(const f16x8*)((char*)Ks + swz128(fj * 16 + c, 4 + g));
      s[fj] = MFMA(k0, qf0, s[fj]);
      s[fj] = MFMA(k1, qf1, s[fj]);
    }
    __builtin_amdgcn_s_setprio(0);
    // row-max: in-register tree over 16, then 2 cross-lane rounds (xor16, xor32)
    float t0 = fmaxf(fmaxf(s[0][0], s[0][1]), fmaxf(s[0][2], s[0][3]));
    float t1 = fmaxf(fmaxf(s[1][0], s[1][1]), fmaxf(s[1][2], s[1][3]));
    float t2 = fmaxf(fmaxf(s[2][0], s[2][1]), fmaxf(s[2][2], s[2][3]));
    float t3 = fmaxf(fmaxf(s[3][0], s[3][1]), fmaxf(s[3][2], s[3][3]));
    float rmax = fmaxf(fmaxf(t0, t1), fmaxf(t2, t3));
    rmax = fmaxf(rmax, __shfl_xor(rmax, 16, 64));
    rmax = fmaxf(rmax, __shfl_xor(rmax, 32, 64));
    // defer-max: only rescale when the running max grows materially (exp2 domain)
    if (__any(rmax > mrun + 11.5f)) {
      float nm = fmaxf(mrun, rmax);
      float corr = exp2f(mrun - nm);
      mrun = nm;
      lrun *= corr;
#pragma unroll
      for (int r = 0; r < 4; ++r) {
        float corr_r = __shfl(corr, bsrc + r, 64);  // corr of row g*4+r
#pragma unroll
        for (int fd = 0; fd < 4; ++fd) po[fd][r] *= corr_r;
      }
    }
    float p[4][4], rs = 0.f;
#pragma unroll
    for (int fj = 0; fj < 4; ++fj) {
      f32x4 pv;
#pragma unroll
      for (int r = 0; r < 4; ++r) {
        pv[r] = exp2f(s[fj][r] - mrun);
        p[fj][r] = pv[r];
      }
      rs += (pv[0] + pv[1]) + (pv[2] + pv[3]);
    }
    rs += __shfl_xor(rs, 16, 64);
    rs += __shfl_xor(rs, 32, 64);
    lrun += rs;
    // P^T -> Ps row c: packed cvt (RTZ) + 8B vector stores; m = fj*16 + g*4 + r
#pragma unroll
    for (int fj = 0; fj < 4; ++fj) {
      u32 lo = __builtin_bit_cast(u32, __builtin_amdgcn_cvt_pkrtz(p[fj][0], p[fj][1]));
      u32 hi = __builtin_bit_cast(u32, __builtin_amdgcn_cvt_pkrtz(p[fj][2], p[fj][3]));
      u32x2 pk; pk[0] = lo; pk[1] = hi;
      int slot = (fj * 16 + g * 4) >> 3;
      *(u32x2*)(Pb + swz128(c, slot) + (g & 1) * 8) = pk;
    }
    asm volatile("s_waitcnt lgkmcnt(0)" ::: "memory");
    __builtin_amdgcn_sched_barrier(0);
    f16x8 pa0 = *(const f16x8*)(Pb + swz128(c, g));
    f16x8 pa1 = *(const f16x8*)(Pb + swz128(c, 4 + g));
    __builtin_amdgcn_s_setprio(1);
#pragma unroll
    for (int fd = 0; fd < 4; ++fd) {
      int dd = fd * 16 + c;
      f16x8 vb0 = *(const f16x8*)((char*)Vs + swz128(dd, g));
      f16x8 vb1 = *(const f16x8*)((char*)Vs + swz128(dd, 4 + g));
      po[fd] = MFMA(pa0, vb0, po[fd]);
      po[fd] = MFMA(pa1, vb1, po[fd]);
    }
    __builtin_amdgcn_s_setprio(0);
  };

  LD(mb, RA);
  for (int tt = 0; tt < 8; tt += 2) {
    __syncthreads();                 // prior tile's LDS reads complete
    ST(RA);
    LD(mb + (tt + 1) * 64, RB);      // prefetch hides under compute
    __syncthreads();
    COMPUTE();
    __syncthreads();
    ST(RB);
    if (tt + 2 < 8) LD(mb + (tt + 2) * 64, RA);
    __syncthreads();
    COMPUTE();
  }

  // epilogue: normalize, transpose through per-wave LDS, vector-store PO rows
  short* PO = (short*)(ws + OFF_PO);
  float* Mm = (float*)(ws + OFF_M);
  float* Ll = (float*)(ws + OFF_L);
  int base = (ms * 16 + bh) * 2048;
  float li[4];
#pragma unroll
  for (int r = 0; r < 4; ++r) li[r] = 1.0f / __shfl(lrun, bsrc + r, 64);
  asm volatile("s_waitcnt lgkmcnt(0)" ::: "memory");  // Pb reads from last COMPUTE done
  __builtin_amdgcn_sched_barrier(0);
#pragma unroll
  for (int fd = 0; fd < 4; ++fd) {
    int d = fd * 16 + c;
#pragma unroll
    for (int r = 0; r < 4; ++r)
      *(short*)(Pb + swz128(g * 4 + r, d >> 3) + (d & 7) * 2) = f2h(po[fd][r] * li[r]);
  }
  asm volatile("s_waitcnt lgkmcnt(0)" ::: "memory");
  __builtin_amdgcn_sched_barrier(0);
  int rr = lane >> 2, ds = (lane & 3) * 16;
  s16x8 v0 = *(const s16x8*)(Pb + swz128(rr, ds >> 3));
  s16x8 v1 = *(const s16x8*)(Pb + swz128(rr, (ds >> 3) + 1));
  *(s16x8*)&PO[(base + nw + rr) * 64 + ds]     = v0;
  *(s16x8*)&PO[(base + nw + rr) * 64 + ds + 8] = v1;
  if (g == 0) {
    Mm[base + nw + c] = mrun;
    Ll[base + nw + c] = lrun;
  }
}

// ------- kernel 3: output projection (64x32), f16 Wm_r, combine fused in B-staging --
__global__ __launch_bounds__(256) void k_final(const float* __restrict__ bm,
    float* __restrict__ out, char* __restrict__ ws) {
  int hid = blockIdx.x + 64 * (blockIdx.y + 4 * blockIdx.z);   // 0..1023
  int fm = (hid & 7) * 128 + (hid >> 3);                       // bijective (1024%8==0)
  int yo = fm & 3, xn = (fm >> 2) & 63, b = fm >> 8;
  int o0 = yo * 64, n0 = xn * 32;
  const short* Wf = (const short*)(ws + OFF_W) + 3 * 65536;    // Wm reordered f16
  const short* PO = (const short*)(ws + OFF_PO);
  const float* Mm = (const float*)(ws + OFF_M);
  const float* Ll = (const float*)(ws + OFF_L);
  __shared__ short As[64 * 64], Bs[32 * 64];
  int t = threadIdx.x, lane = t & 63, g = lane >> 4, c = lane & 15, wave = t >> 6;
  int wr = wave >> 1, wc = wave & 1;
  int arow = t >> 2, aseg = t & 3;
  int brow = t >> 3, bseg = t & 7;
  f32x4 acc[2] = {};
  for (int kk = 0; kk < 4; ++kk) {   // kk = head h; local k = d within head
    __syncthreads();
    // A: f16 Wm_r, coalesced
    const short* wsrc = &Wf[(o0 + arow) * 256 + kk * 64];
    *(s16x8*)((char*)As + swz128(arow, aseg))     = *(const s16x8*)(wsrc + aseg * 8);
    *(s16x8*)((char*)As + swz128(arow, 4 + aseg)) = *(const s16x8*)(wsrc + 32 + aseg * 8);
    // B: combine 4 KV-split partials for row n0+brow, head kk, d = bseg*8..+8
    int bh = b * 4 + kk;
    int nr = n0 + brow;
    float m0 = Mm[(0 * 16 + bh) * 2048 + nr], l0 = Ll[(0 * 16 + bh) * 2048 + nr];
    float m1 = Mm[(1 * 16 + bh) * 2048 + nr], l1 = Ll[(1 * 16 + bh) * 2048 + nr];
    float m2 = Mm[(2 * 16 + bh) * 2048 + nr], l2 = Ll[(2 * 16 + bh) * 2048 + nr];
    float m3 = Mm[(3 * 16 + bh) * 2048 + nr], l3 = Ll[(3 * 16 + bh) * 2048 + nr];
    float M = fmaxf(fmaxf(m0, m1), fmaxf(m2, m3));
    float w0 = l0 * exp2f(m0 - M), w1 = l1 * exp2f(m1 - M);
    float w2 = l2 * exp2f(m2 - M), w3 = l3 * exp2f(m3 - M);
    float inv = 1.f / (w0 + w1 + w2 + w3);
    w0 *= inv; w1 *= inv; w2 *= inv; w3 *= inv;
    s16x8 a0 = *(const s16x8*)&PO[((0 * 16 + bh) * 2048 + nr) * 64 + bseg * 8];
    s16x8 a1 = *(const s16x8*)&PO[((1 * 16 + bh) * 2048 + nr) * 64 + bseg * 8];
    s16x8 a2 = *(const s16x8*)&PO[((2 * 16 + bh) * 2048 + nr) * 64 + bseg * 8];
    s16x8 a3 = *(const s16x8*)&PO[((3 * 16 + bh) * 2048 + nr) * 64 + bseg * 8];
    short hb[8];
#pragma unroll
    for (int j = 0; j < 8; ++j)
      hb[j] = f2h(w0 * h2f(a0[j]) + w1 * h2f(a1[j]) + w2 * h2f(a2[j]) + w3 * h2f(a3[j]));
    *(s16x8*)((char*)Bs + swz128(brow, bseg)) = *(const s16x8*)hb;
    __syncthreads();
#pragma unroll
    for (int ks = 0; ks < 2; ++ks) {
      f16x8 af[2], bfr;
#pragma unroll
      for (int f = 0; f < 2; ++f)
        af[f] = *(const f16x8*)((char*)As + swz128(wr * 32 + f * 16 + c, ks * 4 + g));
      bfr = *(const f16x8*)((char*)Bs + swz128(wc * 16 + c, ks * 4 + g));
#pragma unroll
      for (int i = 0; i < 2; ++i)
        acc[i] = MFMA(af[i], bfr, acc[i]);
    }
  }
#pragma unroll
  for (int i = 0; i < 2; ++i) {
    int ob = o0 + wr * 32 + i * 16 + g * 4;
    int n = n0 + wc * 16 + c;
#pragma unroll
    for (int r = 0; r < 4; ++r)
      out[(b * 256 + ob + r) * 2048 + n] = acc[i][r] + bm[ob + r];
  }
}

extern "C" void kernel_launch(void* const* d_in, const int* in_sizes, int n_in,
                              void* d_out, int out_size, void* d_ws, size_t ws_size,
                              hipStream_t stream) {
  (void)in_sizes; (void)n_in; (void)out_size; (void)ws_size;
  const float* q   = (const float*)d_in[0];
  const float* k   = (const float*)d_in[1];
  const float* v   = (const float*)d_in[2];
  const float* enc = (const float*)d_in[3];
  const float* Wq  = (const float*)d_in[4];
  const float* bq  = (const float*)d_in[5];
  const float* Wk  = (const float*)d_in[6];
  const float* bk  = (const float*)d_in[7];
  const float* Wv  = (const float*)d_in[8];
  const float* bv  = (const float*)d_in[9];
  const float* Wm  = (const float*)d_in[10];
  const float* bm  = (const float*)d_in[11];
  char* ws = (char*)d_ws;
  float* out = (float*)d_out;
  hipLaunchKernelGGL(k_convw, dim3(256, 4), dim3(256), 0, stream, Wq, Wk, Wv, Wm, ws);
  hipLaunchKernelGGL(k_proj, dim3(32, 4, 12), dim3(256), 0, stream, q, k, v, enc, bq, bk, bv, ws);
  hipLaunchKernelGGL(k_attn, dim3(32, 16, 4), dim3(256), 0, stream, ws);
  hipLaunchKernelGGL(k_final, dim3(64, 4, 4), dim3(256), 0, stream, bm, out, ws);
}